// Round 8
// baseline (225.420 us; speedup 1.0000x reference)
//
#include <hip/hip_runtime.h>

// Aggregator: B=8192, H=10, N=25, F=128, D=256 (half=128). Rows = B*H = 81920.
// out[row][0:128]   = relu(x_self[row]          @ w_self  + bias[0:128])
// out[row][128:256] = relu(mean_n(x_neigh[row]) @ w_neigh + bias[128:256])
//
// R8 = R7 (non-temporal stream, 214.8us) + R2 (4x4 register tile).
// At 5.46 TB/s the per-CU LDS pipe (2048 ds_read_b128/block ~ 20k cyc) is
// within 10% of the HBM share (22.3k cyc/block) and likely throttling.
// The 4x4 tile cuts phase-2 LDS traffic 4x (each b128 feeds 16 FMA) and
// makes stores float4-nt. Weights stay cached (reused, L2-hot).

#define RPB 16  // rows per block

typedef float f32x4 __attribute__((ext_vector_type(4)));

__device__ __forceinline__ f32x4 ntload(const f32x4* p) {
    return __builtin_nontemporal_load(p);
}

__device__ __forceinline__ void fma4(float4& a, float s, const float4& b) {
    a.x = fmaf(s, b.x, a.x);
    a.y = fmaf(s, b.y, a.y);
    a.z = fmaf(s, b.z, a.z);
    a.w = fmaf(s, b.w, a.w);
}

__global__ __launch_bounds__(256, 4) void agg_fused_kernel(
    const float* __restrict__ x_self,   // [rows][128]
    const float* __restrict__ x_neigh,  // [rows][25][128]
    const float* __restrict__ w_neigh,  // [128][128]
    const float* __restrict__ w_self,   // [128][128]
    const float* __restrict__ bias,     // [256]
    float* __restrict__ out,            // [rows][256]
    int rows)
{
    __shared__ float xs[RPB][128];
    __shared__ float ag[RPB][128];

    const int tid  = threadIdx.x;
    const int row0 = blockIdx.x * RPB;

    // ---- Phase 1: stage x_self rows and neighbor-mean rows into LDS ----
    // Item space: RPB rows * 32 float4-cols = 512 items; 256 threads * 2 items.
    {
        const f32x4* xs4 = (const f32x4*)x_self;
        const f32x4* xn4 = (const f32x4*)x_neigh;
        #pragma unroll
        for (int it = 0; it < 2; ++it) {
            const int item = tid + it * 256;
            const int r = item >> 5;      // 0..15
            const int v = item & 31;      // float4 column
            const size_t row = (size_t)(row0 + r);

            f32x4 s = ntload(&xs4[row * 32 + v]);
            *(f32x4*)&xs[r][v * 4] = s;

            const size_t base = row * 800 + v;  // float4 units; row stride 25*32
            // 4 independent accumulators -> deeper load/add overlap
            f32x4 a0 = ntload(&xn4[base + 0 * 32]);
            f32x4 a1 = ntload(&xn4[base + 1 * 32]);
            f32x4 a2 = ntload(&xn4[base + 2 * 32]);
            f32x4 a3 = ntload(&xn4[base + 3 * 32]);
            #pragma unroll
            for (int n = 4; n < 24; n += 4) {
                a0 += ntload(&xn4[base + (size_t)(n + 0) * 32]);
                a1 += ntload(&xn4[base + (size_t)(n + 1) * 32]);
                a2 += ntload(&xn4[base + (size_t)(n + 2) * 32]);
                a3 += ntload(&xn4[base + (size_t)(n + 3) * 32]);
            }
            a0 += ntload(&xn4[base + 24 * 32]);
            f32x4 acc = (a0 + a1) + (a2 + a3);
            acc *= (1.0f / 25.0f);
            *(f32x4*)&ag[r][v * 4] = acc;
        }
    }
    __syncthreads();

    // ---- Phase 2: projections, 4x4 register tile per thread ----
    // t: sel = t>>7 (0=self half, 1=neigh half); u = t&127;
    //    cols = 4*(u&31) .. +3 ; rows = 4*(u>>5) .. +3
    const int sel = tid >> 7;
    const int u   = tid & 127;
    const int c0  = (u & 31) * 4;
    const int rg  = (u >> 5) * 4;

    const float* __restrict__ w = sel ? w_neigh : w_self;
    const float (*vec)[128] = sel ? ag : xs;

    float4 acc[4];
    #pragma unroll
    for (int r = 0; r < 4; ++r) acc[r] = make_float4(0.f, 0.f, 0.f, 0.f);

    for (int f4 = 0; f4 < 32; ++f4) {
        // 4 weight rows, float4 over cols: coalesced 512B/wave, L1/L2-hot.
        const float4 w0 = *(const float4*)&w[(f4 * 4 + 0) * 128 + c0];
        const float4 w1 = *(const float4*)&w[(f4 * 4 + 1) * 128 + c0];
        const float4 w2 = *(const float4*)&w[(f4 * 4 + 2) * 128 + c0];
        const float4 w3 = *(const float4*)&w[(f4 * 4 + 3) * 128 + c0];
        #pragma unroll
        for (int r = 0; r < 4; ++r) {
            // 2-way broadcast LDS read (rg has 2 values per wave): conflict-free.
            const float4 xv = *(const float4*)&vec[rg + r][f4 * 4];
            fma4(acc[r], xv.x, w0);
            fma4(acc[r], xv.y, w1);
            fma4(acc[r], xv.z, w2);
            fma4(acc[r], xv.w, w3);
        }
    }

    const float4 b4 = *(const float4*)&bias[sel * 128 + c0];
    #pragma unroll
    for (int r = 0; r < 4; ++r) {
        f32x4 o;
        o.x = fmaxf(acc[r].x + b4.x, 0.f);
        o.y = fmaxf(acc[r].y + b4.y, 0.f);
        o.z = fmaxf(acc[r].z + b4.z, 0.f);
        o.w = fmaxf(acc[r].w + b4.w, 0.f);
        __builtin_nontemporal_store(
            o, (f32x4*)&out[(size_t)(row0 + rg + r) * 256 + sel * 128 + c0]);
    }
}

extern "C" void kernel_launch(void* const* d_in, const int* in_sizes, int n_in,
                              void* d_out, int out_size, void* d_ws, size_t ws_size,
                              hipStream_t stream) {
    const float* x_self  = (const float*)d_in[0];
    const float* x_neigh = (const float*)d_in[1];
    const float* w_neigh = (const float*)d_in[2];
    const float* w_self  = (const float*)d_in[3];
    const float* bias    = (const float*)d_in[4];
    float* out = (float*)d_out;

    const int rows = in_sizes[0] / 128;        // B*H = 81920
    const int blocks = (rows + RPB - 1) / RPB; // 5120

    agg_fused_kernel<<<blocks, 256, 0, stream>>>(
        x_self, x_neigh, w_neigh, w_self, bias, out, rows);
}